// Round 17
// baseline (181.237 us; speedup 1.0000x reference)
//
#include <hip/hip_runtime.h>
#include <float.h>

#define L_TOK 65536
#define DIM   64
#define NCODE 1024
#define KCAP  16

typedef __attribute__((ext_vector_type(8))) short bf16x8;
typedef __attribute__((ext_vector_type(4))) float f32x4;

__device__ __forceinline__ unsigned short f2bf(float f) {
    unsigned u = __float_as_uint(f);
    u += 0x7FFF + ((u >> 16) & 1);          // RNE to bf16 (no NaN inputs)
    return (unsigned short)(u >> 16);
}

// ---------------------------------------------------------------------------
// Kernel A: per-code ||e||^2 (exact fp32 chain) + bf16 copy of embedding.
// ---------------------------------------------------------------------------
__global__ __launch_bounds__(256) void esum_kernel(const float* __restrict__ emb,
                                                   float* __restrict__ esum,
                                                   unsigned short* __restrict__ eb) {
    int n = blockIdx.x * 256 + threadIdx.x;
    if (n >= NCODE) return;
    const float* e = emb + ((size_t)n << 6);
    float s = 0.f;
#pragma unroll
    for (int k = 0; k < DIM; ++k) s = fmaf(e[k], e[k], s);
    esum[n] = s;
#pragma unroll
    for (int k = 0; k < DIM; ++k) eb[(n << 6) + k] = f2bf(e[k]);
}

// ---------------------------------------------------------------------------
// Kernel P: per-token exact ||z||^2 (reference-bitwise chain) + bf16 margin
// M = sum|z| * 2.4e-5 + 6e-5 (passed absmax 0.0 in r16; emax = 1/1024).
// ---------------------------------------------------------------------------
__global__ __launch_bounds__(256) void prep_kernel(const float* __restrict__ z,
                                                   float* __restrict__ zs_out,
                                                   float* __restrict__ marg_out) {
    __shared__ float zl[256][65];
    const int t  = threadIdx.x;
    const int bb = blockIdx.x * 256;
    for (int i = t; i < 4096; i += 256) {
        float4 v = ((const float4*)(z + ((size_t)bb << 6)))[i];
        int tok = i >> 4, k = (i & 15) * 4;
        zl[tok][k] = v.x; zl[tok][k+1] = v.y; zl[tok][k+2] = v.z; zl[tok][k+3] = v.w;
    }
    __syncthreads();
    float zs = 0.f, sa = 0.f;
#pragma unroll
    for (int k = 0; k < DIM; ++k) {
        float v = zl[t][k];
        zs = fmaf(v, v, zs);                // EXACT reference chain order
        sa += fabsf(v);
    }
    zs_out[bb + t]   = zs;
    marg_out[bb + t] = fmaf(sa, 2.4e-5f, 6e-5f);
}

// ---------------------------------------------------------------------------
// Kernel S: MFMA screen (validated r16 layouts; parallelism fixed).
// wave owns 16 tokens; grid 1024 x 4 waves -> 4 blocks/CU = 4 waves/SIMD
// (r16's 140us was 1 wave/SIMD grid starvation: Occupancy 11%).
// Pass 1: d_apx min per token (shfl_xor over the 16 col-lanes).
// Pass 2: identical recompute, ballot d_apx <= min+M, append candidate
// codes to global per-token lists (atomicAdd; ~2/token; KCAP overflow ->
// recheck full-scans that token, so correctness is unconditional).
// ---------------------------------------------------------------------------
__global__ __launch_bounds__(256, 4) void screen_kernel(const float* __restrict__ z,
                                                        const unsigned short* __restrict__ eb,
                                                        const float* __restrict__ esum,
                                                        const float* __restrict__ zs_g,
                                                        const float* __restrict__ marg,
                                                        int* __restrict__ cnt,
                                                        unsigned short* __restrict__ cand) {
    __shared__ float esl[NCODE];            // 4 KB
    const int t    = threadIdx.x;
    const int lane = t & 63;
    const int w    = __builtin_amdgcn_readfirstlane(t >> 6);
    const int tb   = blockIdx.x * 64 + w * 16;   // wave's 16 tokens

    for (int i = t; i < NCODE; i += 256) esl[i] = esum[i];
    __syncthreads();

    const int r16 = lane & 15;
    const int kg  = lane >> 4;

    // A-fragments (r16-validated): row = r16, k = kh*32 + kg*8 + [0,8)
    bf16x8 af0, af1;
    {
        const float* zr = z + ((size_t)(tb + r16) << 6);
        const float* p0 = zr + kg * 8;
        const float* p1 = zr + 32 + kg * 8;
        bf16x8 a0, a1;
#pragma unroll
        for (int i = 0; i < 8; ++i) { a0[i] = (short)f2bf(p0[i]); a1[i] = (short)f2bf(p1[i]); }
        af0 = a0; af1 = a1;
    }
    float zsv[4], thr[4];
#pragma unroll
    for (int r = 0; r < 4; ++r) zsv[r] = zs_g[tb + kg * 4 + r];

    // ---- pass 1: approximate min per token ----
    f32x4 mn = {FLT_MAX, FLT_MAX, FLT_MAX, FLT_MAX};
    for (int ct = 0; ct < 64; ++ct) {
        const unsigned short* ebr = eb + ((size_t)(ct * 16 + r16) << 6) + kg * 8;
        bf16x8 b0 = *(const bf16x8*)(ebr);
        bf16x8 b1 = *(const bf16x8*)(ebr + 32);
        float  es = esl[ct * 16 + r16];
        f32x4 acc = {0.f, 0.f, 0.f, 0.f};
        acc = __builtin_amdgcn_mfma_f32_16x16x32_bf16(af0, b0, acc, 0, 0, 0);
        acc = __builtin_amdgcn_mfma_f32_16x16x32_bf16(af1, b1, acc, 0, 0, 0);
#pragma unroll
        for (int r = 0; r < 4; ++r) {
            float d = fmaf(acc[r], -2.0f, zsv[r] + es);
            mn[r] = fminf(mn[r], d);
        }
    }
#pragma unroll
    for (int r = 0; r < 4; ++r) {
        float v = mn[r];
        v = fminf(v, __shfl_xor(v, 1));
        v = fminf(v, __shfl_xor(v, 2));
        v = fminf(v, __shfl_xor(v, 4));
        v = fminf(v, __shfl_xor(v, 8));
        thr[r] = v + marg[tb + kg * 4 + r];
    }

    // ---- pass 2: ballot candidates into global lists ----
    for (int ct = 0; ct < 64; ++ct) {
        const unsigned short* ebr = eb + ((size_t)(ct * 16 + r16) << 6) + kg * 8;
        bf16x8 b0 = *(const bf16x8*)(ebr);
        bf16x8 b1 = *(const bf16x8*)(ebr + 32);
        float  es = esl[ct * 16 + r16];
        f32x4 acc = {0.f, 0.f, 0.f, 0.f};
        acc = __builtin_amdgcn_mfma_f32_16x16x32_bf16(af0, b0, acc, 0, 0, 0);
        acc = __builtin_amdgcn_mfma_f32_16x16x32_bf16(af1, b1, acc, 0, 0, 0);
#pragma unroll
        for (int r = 0; r < 4; ++r) {
            float d = fmaf(acc[r], -2.0f, zsv[r] + es);
            unsigned long long mask = __ballot(d <= thr[r]);
            if (r16 == 0) {
                unsigned bits = (unsigned)((mask >> (kg * 16)) & 0xFFFFull);
                int tok = tb + kg * 4 + r;
                while (bits) {
                    int b = __builtin_ctz(bits);
                    bits &= bits - 1;
                    int pos = atomicAdd(&cnt[tok], 1);
                    if (pos < KCAP) cand[tok * KCAP + pos] = (unsigned short)(ct * 16 + b);
                }
            }
        }
    }
}

// ---------------------------------------------------------------------------
// Kernel R: exact sparse recheck. thread = token; no LDS; high occupancy.
// d via the reference-bitwise sequential-k fmaf chain; order-independent
// tie-break (d < best) || (d == best && c < bi) == np.argmin first-wins
// (atomic append order is irrelevant). cnt > KCAP -> full exact scan.
// ---------------------------------------------------------------------------
__global__ __launch_bounds__(256) void recheck_kernel(const float* __restrict__ z,
                                                      const float* __restrict__ emb,
                                                      const float* __restrict__ esum,
                                                      const float* __restrict__ zs_g,
                                                      const int* __restrict__ cnt,
                                                      const unsigned short* __restrict__ cand,
                                                      float* __restrict__ idx_out) {
    const int token = blockIdx.x * 256 + threadIdx.x;
    const float* zr = z + ((size_t)token << 6);
    const float  zsx = zs_g[token];
    const int    n   = cnt[token];

    float best = FLT_MAX;
    int   bi   = 0;
    if (n <= KCAP) {
        for (int j = 0; j < n; ++j) {
            int c = cand[token * KCAP + j];
            const float* er = emb + ((size_t)c << 6);
            float a = 0.f;
#pragma unroll
            for (int k = 0; k < DIM; ++k) a = fmaf(zr[k], er[k], a);
            float d = fmaf(a, -2.0f, zsx + esum[c]);
            if (d < best || (d == best && c < bi)) { best = d; bi = c; }
        }
    } else {
        for (int c = 0; c < NCODE; ++c) {              // unconditional fallback
            const float* er = emb + ((size_t)c << 6);
            float a = 0.f;
#pragma unroll
            for (int k = 0; k < DIM; ++k) a = fmaf(zr[k], er[k], a);
            float d = fmaf(a, -2.0f, zsx + esum[c]);
            if (d < best) { best = d; bi = c; }
        }
    }
    idx_out[token] = (float)bi;
}

// ---------------------------------------------------------------------------
// Kernel C: z_q_st + per-block f64 loss partials (unchanged, proven).
// ---------------------------------------------------------------------------
__global__ __launch_bounds__(256) void output_kernel(const float* __restrict__ z,
                                                     const float* __restrict__ emb,
                                                     const float* __restrict__ idx_f,
                                                     float* __restrict__ zq_out,
                                                     double* __restrict__ partials) {
    int gid = blockIdx.x * 256 + threadIdx.x;
    int l = gid >> 6;
    int k = gid & 63;
    int idx = (int)idx_f[l];

    float zv = z[gid];
    float ev = emb[(idx << 6) + k];
    float t    = ev - zv;
    float outv = zv + t;
    zq_out[gid] = outv;

    float sq = t * t;

    __shared__ double red[256];
    red[threadIdx.x] = (double)sq;
    __syncthreads();
    for (int s = 128; s > 0; s >>= 1) {
        if (threadIdx.x < s) red[threadIdx.x] += red[threadIdx.x + s];
        __syncthreads();
    }
    if (threadIdx.x == 0) partials[blockIdx.x] = red[0];
}

// ---------------------------------------------------------------------------
// Kernel D: final deterministic reduction (unchanged, proven).
// ---------------------------------------------------------------------------
__global__ __launch_bounds__(256) void loss_kernel(const double* __restrict__ partials,
                                                   float* __restrict__ loss_out) {
    __shared__ double red[256];
    int t = threadIdx.x;
    double s = 0.0;
    for (int i = 0; i < 64; ++i) s += partials[t * 64 + i];
    red[t] = s;
    __syncthreads();
    for (int st = 128; st > 0; st >>= 1) {
        if (t < st) red[t] += red[t + st];
        __syncthreads();
    }
    if (t == 0) {
        double m  = red[0] / (double)(L_TOK * DIM);
        float  mf = (float)m;
        loss_out[0] = 0.25f * mf + mf;
    }
}

extern "C" void kernel_launch(void* const* d_in, const int* in_sizes, int n_in,
                              void* d_out, int out_size, void* d_ws, size_t ws_size,
                              hipStream_t stream) {
    const float* z   = (const float*)d_in[0];
    const float* emb = (const float*)d_in[1];

    float* out   = (float*)d_out;
    float* zq    = out;                 // [0, 4194304)
    float* loss  = out + 4194304;       // [4194304]
    float* idxf  = out + 4194305;       // [4194305, 4259841)

    char* ws = (char*)d_ws;
    float*          esum     = (float*)ws;                        // @0       4 KB
    unsigned short* eb       = (unsigned short*)(ws + 8192);      // @8K    128 KB
    float*          zs       = (float*)(ws + 139264);             // @136K  256 KB
    float*          marg     = (float*)(ws + 401408);             // @392K  256 KB
    double*         partials = (double*)(ws + 663552);            // @648K  128 KB
    int*            cnt      = (int*)(ws + 794624);               // @776K  256 KB
    unsigned short* cand     = (unsigned short*)(ws + 1056768);   // @1032K   2 MB

    hipMemsetAsync(cnt, 0, L_TOK * sizeof(int), stream);
    esum_kernel   <<<4,     256, 0, stream>>>(emb, esum, eb);
    prep_kernel   <<<256,   256, 0, stream>>>(z, zs, marg);
    screen_kernel <<<1024,  256, 0, stream>>>(z, eb, esum, zs, marg, cnt, cand);
    recheck_kernel<<<256,   256, 0, stream>>>(z, emb, esum, zs, cnt, cand, idxf);
    output_kernel <<<16384, 256, 0, stream>>>(z, emb, idxf, zq, partials);
    loss_kernel   <<<1,     256, 0, stream>>>(partials, loss);
}

// Round 18
// 103.477 us; speedup vs baseline: 1.7515x; 1.7515x over previous
//
#include <hip/hip_runtime.h>
#include <float.h>

#define L_TOK 65536
#define DIM   64
#define NCODE 1024
#define KCAP  16

typedef __attribute__((ext_vector_type(8))) short bf16x8;
typedef __attribute__((ext_vector_type(4))) float f32x4;

__device__ __forceinline__ unsigned short f2bf(float f) {
    unsigned u = __float_as_uint(f);
    u += 0x7FFF + ((u >> 16) & 1);          // RNE to bf16 (no NaN inputs)
    return (unsigned short)(u >> 16);
}

// ---------------------------------------------------------------------------
// Kernel A: per-code ||e||^2 (exact fp32 chain) + bf16 copy of embedding.
// ---------------------------------------------------------------------------
__global__ __launch_bounds__(256) void esum_kernel(const float* __restrict__ emb,
                                                   float* __restrict__ esum,
                                                   unsigned short* __restrict__ eb) {
    int n = blockIdx.x * 256 + threadIdx.x;
    if (n >= NCODE) return;
    const float* e = emb + ((size_t)n << 6);
    float s = 0.f;
#pragma unroll
    for (int k = 0; k < DIM; ++k) s = fmaf(e[k], e[k], s);
    esum[n] = s;
#pragma unroll
    for (int k = 0; k < DIM; ++k) eb[(n << 6) + k] = f2bf(e[k]);
}

// ---------------------------------------------------------------------------
// Kernel P: per-token exact ||z||^2 (reference-bitwise chain) + bf16 margin
// M = sum|z| * 2.4e-5 + 6e-5 (passed absmax 0.0 in r16/r17).
// ---------------------------------------------------------------------------
__global__ __launch_bounds__(256) void prep_kernel(const float* __restrict__ z,
                                                   float* __restrict__ zs_out,
                                                   float* __restrict__ marg_out) {
    __shared__ float zl[256][65];
    const int t  = threadIdx.x;
    const int bb = blockIdx.x * 256;
    for (int i = t; i < 4096; i += 256) {
        float4 v = ((const float4*)(z + ((size_t)bb << 6)))[i];
        int tok = i >> 4, k = (i & 15) * 4;
        zl[tok][k] = v.x; zl[tok][k+1] = v.y; zl[tok][k+2] = v.z; zl[tok][k+3] = v.w;
    }
    __syncthreads();
    float zs = 0.f, sa = 0.f;
#pragma unroll
    for (int k = 0; k < DIM; ++k) {
        float v = zl[t][k];
        zs = fmaf(v, v, zs);                // EXACT reference chain order
        sa += fabsf(v);
    }
    zs_out[bb + t]   = zs;
    marg_out[bb + t] = fmaf(sa, 2.4e-5f, 6e-5f);
}

// ---------------------------------------------------------------------------
// Kernel S: MFMA screen, register-resident B.
// r17 pathology: VGPR=32, each B-fragment loaded from memory for ONE MFMA
// pair -> latency-bound (VALUBusy 15%, MfmaUtil 4.9%).
// Now: block = 512 thr (8 waves) x 128 tokens; wave w holds codes
// [128w,+128) as 8 ct-tiles of B-fragments IN REGISTERS (64 VGPR, loaded
// once) + esv[8]. z staged once as swizzled bf16 in LDS (16 KB); per
// token-tile 2 ds_read_b128 feed 16 MFMAs. No VMEM in the loop.
// zs cancels in screening: q = es - 2a ranks codes identically to d.
// Pass 1: per-wave per-token min(q) -> minw[8][128] -> thr = min + M.
// Pass 2: same registers -> bitwise-identical q, ballot q <= thr, append
// to global per-token lists (r17-proven; KCAP overflow -> full fallback).
// Layouts r16/r17-validated: A row=l&15 k=kh*32+(l>>4)*8; B col=l&15;
// D col=l&15, row=(l>>4)*4+reg.
// ---------------------------------------------------------------------------
__global__ __launch_bounds__(512, 2) void screen_kernel(const float* __restrict__ z,
                                                        const unsigned short* __restrict__ eb,
                                                        const float* __restrict__ esum,
                                                        const float* __restrict__ marg,
                                                        int* __restrict__ cnt,
                                                        unsigned short* __restrict__ cand) {
    __shared__ unsigned short zbf[128 * 64];   // swizzled bf16 [tok][k], 16 KB
    __shared__ float minw[8][128];             // 4 KB
    __shared__ float thr_l[128];               // 0.5 KB

    const int t    = threadIdx.x;
    const int lane = t & 63;
    const int w    = __builtin_amdgcn_readfirstlane(t >> 6);
    const int bb   = blockIdx.x * 128;
    char* zb = (char*)zbf;

    // Stage z -> bf16 LDS, swizzled. thread t: row t>>2, floats [(t&3)*16,+16).
    {
        const int row = t >> 2, q = t & 3;
        const int sw  = (row & 7) << 4;
        const float* zr = z + ((size_t)(bb + row) << 6) + q * 16;
        bf16x8 c0, c1;
#pragma unroll
        for (int i = 0; i < 8; ++i) { c0[i] = (short)f2bf(zr[i]); c1[i] = (short)f2bf(zr[i + 8]); }
        *(bf16x8*)(zb + row * 128 + ((q * 32) ^ sw))      = c0;
        *(bf16x8*)(zb + row * 128 + ((q * 32 + 16) ^ sw)) = c1;
    }

    const int r16 = lane & 15;
    const int kg  = lane >> 4;

    // B-fragments: wave w's 128 codes, loaded ONCE (64 VGPR) + esum (8).
    bf16x8 bq[8][2];
    float  esv[8];
#pragma unroll
    for (int ct = 0; ct < 8; ++ct) {
        const int code = w * 128 + ct * 16 + r16;
        bq[ct][0] = *(const bf16x8*)(eb + ((size_t)code << 6) + kg * 8);
        bq[ct][1] = *(const bf16x8*)(eb + ((size_t)code << 6) + 32 + kg * 8);
        esv[ct]   = esum[code];
    }
    __syncthreads();

    const int sw = (r16 & 7) << 4;   // A-row swizzle term base (row = tile*16+r16)

    // ---- pass 1: per-wave per-token min of q = es - 2a ----
#pragma unroll
    for (int tile = 0; tile < 8; ++tile) {
        const int arow = tile * 16 + r16;
        const int asw  = (arow & 7) << 4;
        bf16x8 af0 = *(const bf16x8*)(zb + arow * 128 + ((kg * 16) ^ asw));
        bf16x8 af1 = *(const bf16x8*)(zb + arow * 128 + ((64 + kg * 16) ^ asw));
        f32x4 mnq = {FLT_MAX, FLT_MAX, FLT_MAX, FLT_MAX};
#pragma unroll
        for (int ct = 0; ct < 8; ++ct) {
            f32x4 acc = {0.f, 0.f, 0.f, 0.f};
            acc = __builtin_amdgcn_mfma_f32_16x16x32_bf16(af0, bq[ct][0], acc, 0, 0, 0);
            acc = __builtin_amdgcn_mfma_f32_16x16x32_bf16(af1, bq[ct][1], acc, 0, 0, 0);
#pragma unroll
            for (int r = 0; r < 4; ++r) {
                float q = fmaf(acc[r], -2.0f, esv[ct]);
                mnq[r] = fminf(mnq[r], q);
            }
        }
#pragma unroll
        for (int r = 0; r < 4; ++r) {
            float v = mnq[r];
            v = fminf(v, __shfl_xor(v, 1));
            v = fminf(v, __shfl_xor(v, 2));
            v = fminf(v, __shfl_xor(v, 4));
            v = fminf(v, __shfl_xor(v, 8));
            if (r16 == 0) minw[w][tile * 16 + kg * 4 + r] = v;
        }
    }
    __syncthreads();
    if (t < 128) {
        float m = minw[0][t];
#pragma unroll
        for (int ww = 1; ww < 8; ++ww) m = fminf(m, minw[ww][t]);
        thr_l[t] = m + marg[bb + t];
    }
    __syncthreads();

    // ---- pass 2: bitwise-identical q, ballot, append candidates ----
#pragma unroll
    for (int tile = 0; tile < 8; ++tile) {
        const int arow = tile * 16 + r16;
        const int asw  = (arow & 7) << 4;
        bf16x8 af0 = *(const bf16x8*)(zb + arow * 128 + ((kg * 16) ^ asw));
        bf16x8 af1 = *(const bf16x8*)(zb + arow * 128 + ((64 + kg * 16) ^ asw));
        float thrv[4];
#pragma unroll
        for (int r = 0; r < 4; ++r) thrv[r] = thr_l[tile * 16 + kg * 4 + r];
#pragma unroll
        for (int ct = 0; ct < 8; ++ct) {
            f32x4 acc = {0.f, 0.f, 0.f, 0.f};
            acc = __builtin_amdgcn_mfma_f32_16x16x32_bf16(af0, bq[ct][0], acc, 0, 0, 0);
            acc = __builtin_amdgcn_mfma_f32_16x16x32_bf16(af1, bq[ct][1], acc, 0, 0, 0);
#pragma unroll
            for (int r = 0; r < 4; ++r) {
                float q = fmaf(acc[r], -2.0f, esv[ct]);
                unsigned long long mask = __ballot(q <= thrv[r]);
                if (r16 == 0) {
                    unsigned bits = (unsigned)((mask >> (kg * 16)) & 0xFFFFull);
                    int tok = bb + tile * 16 + kg * 4 + r;
                    while (bits) {
                        int b = __builtin_ctz(bits);
                        bits &= bits - 1;
                        int pos = atomicAdd(&cnt[tok], 1);
                        if (pos < KCAP) cand[tok * KCAP + pos] = (unsigned short)(w * 128 + ct * 16 + b);
                    }
                }
            }
        }
    }
    (void)sw;
}

// ---------------------------------------------------------------------------
// Kernel R: exact sparse recheck (r17-proven, unchanged).
// ---------------------------------------------------------------------------
__global__ __launch_bounds__(256) void recheck_kernel(const float* __restrict__ z,
                                                      const float* __restrict__ emb,
                                                      const float* __restrict__ esum,
                                                      const float* __restrict__ zs_g,
                                                      const int* __restrict__ cnt,
                                                      const unsigned short* __restrict__ cand,
                                                      float* __restrict__ idx_out) {
    const int token = blockIdx.x * 256 + threadIdx.x;
    const float* zr = z + ((size_t)token << 6);
    const float  zsx = zs_g[token];
    const int    n   = cnt[token];

    float best = FLT_MAX;
    int   bi   = 0;
    if (n <= KCAP) {
        for (int j = 0; j < n; ++j) {
            int c = cand[token * KCAP + j];
            const float* er = emb + ((size_t)c << 6);
            float a = 0.f;
#pragma unroll
            for (int k = 0; k < DIM; ++k) a = fmaf(zr[k], er[k], a);
            float d = fmaf(a, -2.0f, zsx + esum[c]);
            if (d < best || (d == best && c < bi)) { best = d; bi = c; }
        }
    } else {
        for (int c = 0; c < NCODE; ++c) {
            const float* er = emb + ((size_t)c << 6);
            float a = 0.f;
#pragma unroll
            for (int k = 0; k < DIM; ++k) a = fmaf(zr[k], er[k], a);
            float d = fmaf(a, -2.0f, zsx + esum[c]);
            if (d < best) { best = d; bi = c; }
        }
    }
    idx_out[token] = (float)bi;
}

// ---------------------------------------------------------------------------
// Kernel C: z_q_st + per-block f64 loss partials (unchanged, proven).
// ---------------------------------------------------------------------------
__global__ __launch_bounds__(256) void output_kernel(const float* __restrict__ z,
                                                     const float* __restrict__ emb,
                                                     const float* __restrict__ idx_f,
                                                     float* __restrict__ zq_out,
                                                     double* __restrict__ partials) {
    int gid = blockIdx.x * 256 + threadIdx.x;
    int l = gid >> 6;
    int k = gid & 63;
    int idx = (int)idx_f[l];

    float zv = z[gid];
    float ev = emb[(idx << 6) + k];
    float t    = ev - zv;
    float outv = zv + t;
    zq_out[gid] = outv;

    float sq = t * t;

    __shared__ double red[256];
    red[threadIdx.x] = (double)sq;
    __syncthreads();
    for (int s = 128; s > 0; s >>= 1) {
        if (threadIdx.x < s) red[threadIdx.x] += red[threadIdx.x + s];
        __syncthreads();
    }
    if (threadIdx.x == 0) partials[blockIdx.x] = red[0];
}

// ---------------------------------------------------------------------------
// Kernel D: final deterministic reduction (unchanged, proven).
// ---------------------------------------------------------------------------
__global__ __launch_bounds__(256) void loss_kernel(const double* __restrict__ partials,
                                                   float* __restrict__ loss_out) {
    __shared__ double red[256];
    int t = threadIdx.x;
    double s = 0.0;
    for (int i = 0; i < 64; ++i) s += partials[t * 64 + i];
    red[t] = s;
    __syncthreads();
    for (int st = 128; st > 0; st >>= 1) {
        if (t < st) red[t] += red[t + st];
        __syncthreads();
    }
    if (t == 0) {
        double m  = red[0] / (double)(L_TOK * DIM);
        float  mf = (float)m;
        loss_out[0] = 0.25f * mf + mf;
    }
}

extern "C" void kernel_launch(void* const* d_in, const int* in_sizes, int n_in,
                              void* d_out, int out_size, void* d_ws, size_t ws_size,
                              hipStream_t stream) {
    const float* z   = (const float*)d_in[0];
    const float* emb = (const float*)d_in[1];

    float* out   = (float*)d_out;
    float* zq    = out;                 // [0, 4194304)
    float* loss  = out + 4194304;       // [4194304]
    float* idxf  = out + 4194305;       // [4194305, 4259841)

    char* ws = (char*)d_ws;
    float*          esum     = (float*)ws;                        // @0       4 KB
    unsigned short* eb       = (unsigned short*)(ws + 8192);      // @8K    128 KB
    float*          zs       = (float*)(ws + 139264);             // @136K  256 KB
    float*          marg     = (float*)(ws + 401408);             // @392K  256 KB
    double*         partials = (double*)(ws + 663552);            // @648K  128 KB
    int*            cnt      = (int*)(ws + 794624);               // @776K  256 KB
    unsigned short* cand     = (unsigned short*)(ws + 1056768);   // @1032K   2 MB

    hipMemsetAsync(cnt, 0, L_TOK * sizeof(int), stream);
    esum_kernel   <<<4,     256, 0, stream>>>(emb, esum, eb);
    prep_kernel   <<<256,   256, 0, stream>>>(z, zs, marg);
    screen_kernel <<<512,   512, 0, stream>>>(z, eb, esum, marg, cnt, cand);
    recheck_kernel<<<256,   256, 0, stream>>>(z, emb, esum, zs, cnt, cand, idxf);
    output_kernel <<<16384, 256, 0, stream>>>(z, emb, idxf, zq, partials);
    loss_kernel   <<<1,     256, 0, stream>>>(partials, loss);
}